// Round 9
// baseline (9877.336 us; speedup 1.0000x reference)
//
#include <hip/hip_runtime.h>
#include <math.h>

// ---------------- problem constants ----------------
#define T_LEN 2048
#define NTH   512    // 8 waves: w0-3 L0 (wave-private 4-hid tiles), w4-7 L1
// 256 blocks: gang = bid>>4 (0..15), slice = bid&15
// context A = group gang (batches gang*4..+3), context B = group gang+16
// 32 groups x 4 batches = 128; 16 hidden/layer/block (16 slices x 16 = 256)

typedef __attribute__((ext_vector_type(8))) short short8v;  // 8 bf16
typedef __attribute__((ext_vector_type(4))) float f32x4;
typedef unsigned int u32t;
typedef unsigned long long u64t;

// ---------------- ws layout (u32 units) ----------------
// h element: packed u32 = (bf16hi<<16) | bf16lo. Depth-4 step slots.
#define HA1 0            // [4 slots][16 gang][4 batch][256 hid] = 65536 u32
#define HA2 65536
#define HB1 131072
#define HB2 196608
#define FLA 262144       // [16 gang][32] flags (one 128B line per gang)
#define FLB 262656
#define ABT 263168
#define WS_U32 263169    // ~1.03 MB

// ---------------- LDS ----------------
// ctx c at c*32768: 4 planes (h1hi,h1lo,h2hi,h2lo) x [16 rows][512 B], XOR-swizzled.
// rows 4..15 permanently zero (BPG=4). 64 KB used; allocate 128 KB -> 1 block/CU.

__device__ __forceinline__ float fsigm(float x) {
  return __builtin_amdgcn_rcpf(1.0f + __builtin_amdgcn_exp2f(-1.44269504f * x));
}
__device__ __forceinline__ float ftanh(float x) {
  return fmaf(-2.0f, __builtin_amdgcn_rcpf(1.0f + __builtin_amdgcn_exp2f(2.88539009f * x)), 1.0f);
}
__device__ __forceinline__ u32t bf_rn(float x) {
  u32t b; __builtin_memcpy(&b, &x, 4);
  return (b + 0x7FFFu + ((b >> 16) & 1u)) >> 16;
}
__device__ __forceinline__ void split_bf(float x, u32t& hi, u32t& lo) {
  hi = bf_rn(x);
  u32t hb = hi << 16; float hf; __builtin_memcpy(&hf, &hb, 4);
  lo = bf_rn(x - hf);
}

__global__ void init_ws_kernel(u32t* ws) {
  for (int i = blockIdx.x * blockDim.x + threadIdx.x; i < WS_U32;
       i += gridDim.x * blockDim.x)
    ws[i] = 0u;
}

#define MFMA16(a, b, c) __builtin_amdgcn_mfma_f32_16x16x32_bf16(a, b, c, 0, 0, 0)
#define ALD32(ptr) __hip_atomic_load((ptr), __ATOMIC_RELAXED, __HIP_MEMORY_SCOPE_AGENT)
#define ALD64(ptr) __hip_atomic_load((ptr), __ATOMIC_RELAXED, __HIP_MEMORY_SCOPE_AGENT)
#define AST32(ptr, v) __hip_atomic_store((ptr), (v), __ATOMIC_RELAXED, __HIP_MEMORY_SCOPE_AGENT)

__launch_bounds__(NTH, 2)
__global__ void lstm_persist(const float* __restrict__ y,
                             const float* __restrict__ Wih0, const float* __restrict__ Whh0,
                             const float* __restrict__ bih0, const float* __restrict__ bhh0,
                             const float* __restrict__ Wih1, const float* __restrict__ Whh1,
                             const float* __restrict__ bih1, const float* __restrict__ bhh1,
                             const float* __restrict__ Wfc, const float* __restrict__ bfc,
                             float* __restrict__ out, u32t* wsu) {
  extern __shared__ char lds[];
  const int tid   = threadIdx.x;
  const int lane  = tid & 63;
  const int wid   = tid >> 6;
  const int gang  = blockIdx.x >> 4;
  const int slice = blockIdx.x & 15;
  const int gA    = gang;          // context A group
  const int gB    = gang + 16;     // context B group

  u32t* hA1 = wsu + HA1; u32t* hA2 = wsu + HA2;
  u32t* hB1 = wsu + HB1; u32t* hB2 = wsu + HB2;
  u32t* flgA = wsu + FLA + gang * 32;
  u32t* flgB = wsu + FLB + gang * 32;
  u32t* abortf = wsu + ABT;

  // zero staging (initial h = 0; rows 4..15 permanently zero)
  for (int i = tid; i < 16384; i += NTH) ((u32t*)lds)[i] = 0u;

  const bool isL1 = (wid >= 4);
  const int  m = lane & 15, kq4 = lane >> 4;
  const int  gate = m & 3, hs4 = m >> 2;           // A row m = hs4*4 + gate
  const int  hidb = slice * 16 + (wid & 3) * 4;
  const int  grow = gate * 256 + hidb + hs4;

  // ---- A-fragment preload (split hi/lo bf16), full K per wave; shared by contexts ----
  const float* WA = isL1 ? Wih1 : Whh0;
  const float* WB = isL1 ? Whh1 : Wfc;
  const int   rowB   = isL1 ? grow : m;
  const bool  bValid = isL1 || (wid == 0 && m < 2);

  short8v ahi[16], alo[16];
  #pragma unroll
  for (int ks = 0; ks < 8; ++ks) {
    short8v h0, l0, h1, l1;
    #pragma unroll
    for (int j = 0; j < 8; ++j) {
      int k = ks * 32 + kq4 * 8 + j;
      u32t hi, lo;
      split_bf(WA[grow * 256 + k], hi, lo);
      h0[j] = (short)hi; l0[j] = (short)lo;
      float vb = bValid ? WB[rowB * 256 + k] : 0.f;
      split_bf(vb, hi, lo);
      h1[j] = (short)hi; l1[j] = (short)lo;
    }
    ahi[ks] = h0;     alo[ks] = l0;
    ahi[8 + ks] = h1; alo[8 + ks] = l1;
  }

  // ---- per-lane epilogue preloads (C: col=lane&15=batch, row=kq4*4+reg=gate) ----
  const int hidC = hidb + kq4;
  float bias4[4], wx[16];
  #pragma unroll
  for (int r = 0; r < 4; ++r) {
    int row = r * 256 + hidC;
    bias4[r] = isL1 ? (bih1[row] + bhh1[row]) : (bih0[row] + bhh0[row]);
    #pragma unroll
    for (int kk = 0; kk < 4; ++kk)
      wx[r * 4 + kk] = isL1 ? 0.f : Wih0[row * 4 + kk];
  }
  float bfc0 = 0.f, bfc1 = 0.f;
  if (wid == 0) { bfc0 = bfc[0]; bfc1 = bfc[1]; }
  const float* ybA = y + (gA * 4 + (m & 3)) * T_LEN;
  const float* ybB = y + (gB * 4 + (m & 3)) * T_LEN;

  float cstA = 0.f, cstB = 0.f;

  // staging map: thread -> (batch row 0..3, 2 consecutive hid elems)
  const int srow = tid >> 7;
  const int sc2  = (tid & 127) * 2;
  const int soff = srow * 512 + (((tid & 127) * 4) ^ (srow << 4));  // byte, swizzled
  // B-frag read map
  const int brow = lane & 15;
  const int bxr  = (brow & 7) << 4;
  const int bco  = kq4 * 16;

#define BRD(sb, pl, ks) \
  (*(const short8v*)((sb) + (pl) * 8192 + brow * 512 + ((((ks) * 64) + bco) ^ bxr)))

  // one pipeline section: compute self ctx at phase sp; prefetch other ctx data for
  // phase qq (flag-gated); unpack into other ctx's LDS; ends with barrier.
  auto section = [&](const char* sbR, char* sbW,
                     u32t* sH1, u32t* sH2,                 // self h store buffers
                     const u32t* oH1, const u32t* oH2,     // other ctx h load buffers
                     u32t* pf, int sp, int qq,
                     float& cst, const float* yb, int G) {
    const bool act = isL1 ? (sp >= 1 && sp <= T_LEN) : (sp < T_LEN);

    // ---- MFMA (3-term split precision) ----
    f32x4 accP = {0.f, 0.f, 0.f, 0.f}, accQ = {0.f, 0.f, 0.f, 0.f};
    if (act) {
      if (!isL1) {
        #pragma unroll
        for (int ks = 0; ks < 8; ++ks) {
          short8v bh = BRD(sbR, 0, ks), bl = BRD(sbR, 1, ks);
          accP = MFMA16(ahi[ks], bh, accP);
          accQ = MFMA16(ahi[ks], bl, accQ);
          accQ = MFMA16(alo[ks], bh, accQ);
        }
      } else {
        #pragma unroll
        for (int ks = 0; ks < 8; ++ks) {
          short8v b1h = BRD(sbR, 0, ks), b1l = BRD(sbR, 1, ks);
          short8v b2h = BRD(sbR, 2, ks), b2l = BRD(sbR, 3, ks);
          accP = MFMA16(ahi[ks], b1h, accP);
          accQ = MFMA16(ahi[ks], b1l, accQ);
          accQ = MFMA16(alo[ks], b1h, accQ);
          accP = MFMA16(ahi[8 + ks], b2h, accP);
          accQ = MFMA16(ahi[8 + ks], b2l, accQ);
          accQ = MFMA16(alo[8 + ks], b2h, accQ);
        }
      }
    }

    // ---- flag-gated prefetch of other ctx (flag published a section ago) ----
    const bool ld1 = (qq >= 1 && qq <= T_LEN);
    const bool ld2 = (qq >= 2 && qq <= T_LEN + 1);
    u64t v1 = 0, v2 = 0;
    if (ld1 | ld2) {
      const u32t tgt = (u32t)qq;
      int guard = 0;
      for (;;) {
        u32t f = ALD32(&pf[lane & 15]);
        if (__all((int)(f >= tgt || (lane & 15) == slice))) break;  // own slice implied
        if (++guard > (1 << 18)) {
          AST32(abortf, 1u);
          break;
        }
        if ((guard & 31) == 0 && ALD32(abortf) != 0) break;
        __builtin_amdgcn_s_sleep(2);
      }
      if (ld1)
        v1 = ALD64((const u64t*)(oH1 + ((qq - 1) & 3) * 16384 + gang * 1024 + srow * 256 + sc2));
      if (ld2)
        v2 = ALD64((const u64t*)(oH2 + ((qq - 2) & 3) * 16384 + gang * 1024 + srow * 256 + sc2));
    }

    // ---- nonlinearity + cell update + h store (plain packed u32) ----
    if (act) {
      float g[4];
      #pragma unroll
      for (int r = 0; r < 4; ++r) g[r] = accP[r] + accQ[r] + bias4[r];
      if (!isL1) {
        float xx[4];
        #pragma unroll
        for (int kk = 0; kk < 4; ++kk) {
          int ti = sp + kk - 3;
          xx[kk] = (ti >= 0) ? yb[ti] : -100.0f;
        }
        #pragma unroll
        for (int kk = 0; kk < 4; ++kk)
          #pragma unroll
          for (int r = 0; r < 4; ++r) g[r] = fmaf(wx[r * 4 + kk], xx[kk], g[r]);
      }
      cst = fsigm(g[1]) * cst + fsigm(g[0]) * ftanh(g[2]);
      float hv = fsigm(g[3]) * ftanh(cst);
      if (m < 4) {
        u32t hi, lo; split_bf(hv, hi, lo);
        u32t pk = (hi << 16) | lo;
        u32t* dst = isL1
            ? (sH2 + ((sp - 1) & 3) * 16384 + gang * 1024 + m * 256 + hidC)
            : (sH1 + (sp & 3) * 16384 + gang * 1024 + m * 256 + hidC);
        AST32(dst, pk);
      }
    }

    // ---- FC (w0, rotating slice) ----
    if (wid == 0 && sp >= 2 && slice == ((sp - 2) & 15)) {
      f32x4 aF = {0.f, 0.f, 0.f, 0.f}, aG = {0.f, 0.f, 0.f, 0.f};
      #pragma unroll
      for (int ks = 0; ks < 8; ++ks) {
        short8v b2h = BRD(sbR, 2, ks), b2l = BRD(sbR, 3, ks);
        aF = MFMA16(ahi[8 + ks], b2h, aF);
        aG = MFMA16(ahi[8 + ks], b2l, aG);
        aG = MFMA16(alo[8 + ks], b2h, aG);
      }
      if (lane < 4) {
        float2 o;
        o.x = aF[0] + aG[0] + bfc0;
        o.y = aF[1] + aG[1] + bfc1;
        *(float2*)(&out[(G * 4 + lane) * (T_LEN * 2) + (sp - 2) * 2]) = o;
      }
    }

    // ---- drain (stores acked + loads arrived), unpack, barrier ----
    asm volatile("s_waitcnt vmcnt(0)" ::: "memory");
    if (ld1) {
      u32t e0 = (u32t)v1, e1 = (u32t)(v1 >> 32);
      *(u32t*)(sbW + soff)        = (e0 >> 16) | (e1 & 0xFFFF0000u);
      *(u32t*)(sbW + 8192 + soff) = (e0 & 0xFFFFu) | (e1 << 16);
    }
    if (ld2) {
      u32t e0 = (u32t)v2, e1 = (u32t)(v2 >> 32);
      *(u32t*)(sbW + 16384 + soff) = (e0 >> 16) | (e1 & 0xFFFF0000u);
      *(u32t*)(sbW + 24576 + soff) = (e0 & 0xFFFFu) | (e1 << 16);
    }
    __syncthreads();
  };

  char* LA = lds;
  char* LB = lds + 32768;

  __syncthreads();

  for (int p = 0; p <= T_LEN + 1; ++p) {
    // ---- section A: compute gA(p); prefetch B-data for secB(p) ----
    if (tid == 0 && p > 0) AST32(&flgB[slice], (u32t)p);       // certify secB(p-1)
    section(LA, LB, hA1, hA2, hB1, hB2, flgB, p, p, cstA, ybA, gA);
    // ---- section B: compute gB(p); prefetch A-data for secA(p+1) ----
    if (tid == 0) AST32(&flgA[slice], (u32t)(p + 1));          // certify secA(p)
    section(LB, LA, hB1, hB2, hA1, hA2, flgA, p, p + 1, cstB, ybB, gB);
  }
}

extern "C" void kernel_launch(void* const* d_in, const int* in_sizes, int n_in,
                              void* d_out, int out_size, void* d_ws, size_t ws_size,
                              hipStream_t stream) {
  const float* y    = (const float*)d_in[0];
  const float* Wih0 = (const float*)d_in[1];
  const float* Whh0 = (const float*)d_in[2];
  const float* bih0 = (const float*)d_in[3];
  const float* bhh0 = (const float*)d_in[4];
  const float* Wih1 = (const float*)d_in[5];
  const float* Whh1 = (const float*)d_in[6];
  const float* bih1 = (const float*)d_in[7];
  const float* bhh1 = (const float*)d_in[8];
  const float* Wfc  = (const float*)d_in[9];
  const float* bfc  = (const float*)d_in[10];
  float* out = (float*)d_out;
  u32t*  ws  = (u32t*)d_ws;

  (void)hipFuncSetAttribute(reinterpret_cast<const void*>(lstm_persist),
                            hipFuncAttributeMaxDynamicSharedMemorySize, 131072);

  hipLaunchKernelGGL(init_ws_kernel, dim3(256), dim3(256), 0, stream, ws);
  hipLaunchKernelGGL(lstm_persist, dim3(256), dim3(NTH), 131072, stream,
                     y, Wih0, Whh0, bih0, bhh0, Wih1, Whh1, bih1, bhh1,
                     Wfc, bfc, out, ws);
}

// Round 10
// 7283.559 us; speedup vs baseline: 1.3561x; 1.3561x over previous
//
#include <hip/hip_runtime.h>
#include <math.h>

// ---------------- problem constants ----------------
#define T_LEN 2048
#define NTH   512
// 256 blocks: gang = bid>>4 (0..15), slice = bid&15 (16 hid/layer/block)
// ctxA = group gang (batches gang*4..+3), ctxB = group gang+16. 32 grp x 4 = 128.
// 8 waves: w0-3 L0 tile (wid&3), w4-7 L1 tile. Per-wave finishers.

typedef __attribute__((ext_vector_type(8))) short short8v;  // 8 bf16
typedef __attribute__((ext_vector_type(4))) float f32x4;
typedef unsigned int u32t;
typedef unsigned long long u64t;

// ---------------- ws layout (u32 units) ----------------
// h element: fp32 bits of h (|h|<1 => bit30==0) | gen<<30, gen=(step>>2)&1.
// step s lives in slot s&3. Init = 0x40000000 (gen=1, stale for first writes).
#define H1_OFF  0            // [4 slots][32 grp][4 batch][256 hid] = 131072 u32
#define H2_OFF  131072
#define ABT_OFF 262144
#define WS_U32  262145       // ~1.05 MB

// ---------------- LDS ----------------
// ctx c at c*32768: 4 planes (h1hi,h1lo,h2hi,h2lo) x [16 rows][512 B], XOR-swizzled.
// rows 4..15 permanently zero (4 batches/ctx). 64 KB used; alloc 128 KB -> 1 block/CU.

__device__ __forceinline__ float fsigm(float x) {
  return __builtin_amdgcn_rcpf(1.0f + __builtin_amdgcn_exp2f(-1.44269504f * x));
}
__device__ __forceinline__ float ftanh(float x) {
  return fmaf(-2.0f, __builtin_amdgcn_rcpf(1.0f + __builtin_amdgcn_exp2f(2.88539009f * x)), 1.0f);
}
__device__ __forceinline__ u32t bf_rn(float x) {
  u32t b; __builtin_memcpy(&b, &x, 4);
  return (b + 0x7FFFu + ((b >> 16) & 1u)) >> 16;
}
__device__ __forceinline__ void split_bf(float x, u32t& hi, u32t& lo) {
  hi = bf_rn(x);
  u32t hb = hi << 16; float hf; __builtin_memcpy(&hf, &hb, 4);
  lo = bf_rn(x - hf);
}

__global__ void init_ws_kernel(u32t* ws) {
  for (int i = blockIdx.x * blockDim.x + threadIdx.x; i < WS_U32;
       i += gridDim.x * blockDim.x)
    ws[i] = (i < ABT_OFF) ? 0x40000000u : 0u;
}

#define MFMA16(a, b, c) __builtin_amdgcn_mfma_f32_16x16x32_bf16(a, b, c, 0, 0, 0)
#define ALD64(ptr) __hip_atomic_load((ptr), __ATOMIC_RELAXED, __HIP_MEMORY_SCOPE_AGENT)
#define ALD32(ptr) __hip_atomic_load((ptr), __ATOMIC_RELAXED, __HIP_MEMORY_SCOPE_AGENT)
#define AST32(ptr, v) __hip_atomic_store((ptr), (v), __ATOMIC_RELAXED, __HIP_MEMORY_SCOPE_AGENT)

__launch_bounds__(NTH, 2)
__global__ void lstm_persist(const float* __restrict__ y,
                             const float* __restrict__ Wih0, const float* __restrict__ Whh0,
                             const float* __restrict__ bih0, const float* __restrict__ bhh0,
                             const float* __restrict__ Wih1, const float* __restrict__ Whh1,
                             const float* __restrict__ bih1, const float* __restrict__ bhh1,
                             const float* __restrict__ Wfc, const float* __restrict__ bfc,
                             float* __restrict__ out, u32t* wsu) {
  extern __shared__ char lds[];
  const int tid   = threadIdx.x;
  const int lane  = tid & 63;
  const int wid   = tid >> 6;
  const int gang  = blockIdx.x >> 4;
  const int slice = blockIdx.x & 15;
  const int gA    = gang;
  const int gB    = gang + 16;

  u32t* h1b    = wsu + H1_OFF;
  u32t* h2b    = wsu + H2_OFF;
  u32t* abortf = wsu + ABT_OFF;

  // zero staging (initial h = 0; rows 4..15 permanently zero)
  for (int i = tid; i < 16384; i += NTH) ((u32t*)lds)[i] = 0u;

  const bool isL1 = (wid >= 4);
  const int  m = lane & 15, kq4 = lane >> 4;
  const int  gate = m & 3, hs4 = m >> 2;           // A row m = hs4*4 + gate
  const int  hidb = slice * 16 + (wid & 3) * 4;
  const int  grow = gate * 256 + hidb + hs4;

  // ---- A-fragment preload (split hi/lo bf16), full K; shared by both contexts ----
  const float* WA = isL1 ? Wih1 : Whh0;
  const float* WB = isL1 ? Whh1 : Wfc;
  const int   rowB   = isL1 ? grow : m;
  const bool  bValid = isL1 || (wid == 0 && m < 2);

  short8v ahi[16], alo[16];
  #pragma unroll
  for (int ks = 0; ks < 8; ++ks) {
    short8v h0, l0, h1, l1;
    #pragma unroll
    for (int j = 0; j < 8; ++j) {
      int k = ks * 32 + kq4 * 8 + j;
      u32t hi, lo;
      split_bf(WA[grow * 256 + k], hi, lo);
      h0[j] = (short)hi; l0[j] = (short)lo;
      float vb = bValid ? WB[rowB * 256 + k] : 0.f;
      split_bf(vb, hi, lo);
      h1[j] = (short)hi; l1[j] = (short)lo;
    }
    ahi[ks] = h0;     alo[ks] = l0;
    ahi[8 + ks] = h1; alo[8 + ks] = l1;
  }

  // ---- per-lane epilogue preloads (C: col=lane&15=batch, row=kq4*4+reg) ----
  const int hidC = hidb + kq4;
  float bias4[4], wx[16];
  #pragma unroll
  for (int r = 0; r < 4; ++r) {
    int row = r * 256 + hidC;
    bias4[r] = isL1 ? (bih1[row] + bhh1[row]) : (bih0[row] + bhh0[row]);
    #pragma unroll
    for (int kk = 0; kk < 4; ++kk)
      wx[r * 4 + kk] = isL1 ? 0.f : Wih0[row * 4 + kk];
  }
  float bfc0 = 0.f, bfc1 = 0.f;
  if (wid == 0) { bfc0 = bfc[0]; bfc1 = bfc[1]; }
  const float* ybA = y + (gA * 4 + (m & 3)) * T_LEN;
  const float* ybB = y + (gB * 4 + (m & 3)) * T_LEN;

  float cstA = 0.f, cstB = 0.f;

  // staging map: thread -> (batch row 0..3, 2 consecutive hid elems)
  const int srow = tid >> 7;
  const int sc2  = (tid & 127) * 2;
  const int soff = srow * 512 + (((tid & 127) * 4) ^ (srow << 4));  // byte, swizzled
  // B-frag read map
  const int brow = lane & 15;
  const int bxr  = (brow & 7) << 4;
  const int bco  = kq4 * 16;

#define BRD(sb, pl, ks) \
  (*(const short8v*)((sb) + (pl) * 8192 + brow * 512 + ((((ks) * 64) + bco) ^ bxr)))

  // one section: compute self ctx at phase sp (reads sbR); store h (gen-tagged);
  // issue+check other ctx's data for its phase qp; unpack into sbW; barrier.
  auto section = [&](const char* sbR, char* sbW, int sG, int oG, int sp, int qp,
                     float& cst, const float* yb) {
    const bool act = isL1 ? (sp >= 1 && sp <= T_LEN) : (sp < T_LEN);

    // ---- MFMA (3-term split precision) ----
    f32x4 accP = {0.f, 0.f, 0.f, 0.f}, accQ = {0.f, 0.f, 0.f, 0.f};
    if (act) {
      if (!isL1) {
        #pragma unroll
        for (int ks = 0; ks < 8; ++ks) {
          short8v bh = BRD(sbR, 0, ks), bl = BRD(sbR, 1, ks);
          accP = MFMA16(ahi[ks], bh, accP);
          accQ = MFMA16(ahi[ks], bl, accQ);
          accQ = MFMA16(alo[ks], bh, accQ);
        }
      } else {
        #pragma unroll
        for (int ks = 0; ks < 8; ++ks) {
          short8v b1h = BRD(sbR, 0, ks), b1l = BRD(sbR, 1, ks);
          short8v b2h = BRD(sbR, 2, ks), b2l = BRD(sbR, 3, ks);
          accP = MFMA16(ahi[ks], b1h, accP);
          accQ = MFMA16(ahi[ks], b1l, accQ);
          accQ = MFMA16(alo[ks], b1h, accQ);
          accP = MFMA16(ahi[8 + ks], b2h, accP);
          accQ = MFMA16(ahi[8 + ks], b2l, accQ);
          accQ = MFMA16(alo[8 + ks], b2h, accQ);
        }
      }
    }

    // ---- nonlinearity + cell update + gen-tagged h store (fire-and-forget) ----
    if (act) {
      float g[4];
      #pragma unroll
      for (int r = 0; r < 4; ++r) g[r] = accP[r] + accQ[r] + bias4[r];
      if (!isL1) {
        float xx[4];
        #pragma unroll
        for (int kk = 0; kk < 4; ++kk) {
          int ti = sp + kk - 3;
          xx[kk] = (ti >= 0) ? yb[ti] : -100.0f;
        }
        #pragma unroll
        for (int kk = 0; kk < 4; ++kk)
          #pragma unroll
          for (int r = 0; r < 4; ++r) g[r] = fmaf(wx[r * 4 + kk], xx[kk], g[r]);
      }
      cst = fsigm(g[1]) * cst + fsigm(g[0]) * ftanh(g[2]);
      float hv = fsigm(g[3]) * ftanh(cst);
      if (m < 4) {
        const int step = isL1 ? (sp - 1) : sp;
        u32t w; __builtin_memcpy(&w, &hv, 4);          // |hv|<1 => bit30 == 0
        w |= ((u32t)((step >> 2) & 1)) << 30;          // embed generation bit
        u32t* dst = (isL1 ? h2b : h1b) + (step & 3) * 32768 + sG * 1024 + m * 256 + hidC;
        AST32(dst, w);
      }
    }

    // ---- issue other-ctx loads (data stored >= one section ago) ----
    const bool ld1 = (qp >= 1 && qp <= T_LEN);
    const bool ld2 = (qp >= 2 && qp <= T_LEN + 1);
    const u64t* s1 = (const u64t*)(h1b + ((qp - 1) & 3) * 32768 + oG * 1024 + srow * 256 + sc2);
    const u64t* s2 = (const u64t*)(h2b + ((qp - 2) & 3) * 32768 + oG * 1024 + srow * 256 + sc2);
    u64t v1 = 0, v2 = 0;
    if (ld1) v1 = ALD64(s1);
    if (ld2) v2 = ALD64(s2);

    // ---- FC (self ctx, w0, rotating slice; off the h critical path) ----
    if (wid == 0 && sp >= 2 && slice == ((sp - 2) & 15)) {
      f32x4 aF = {0.f, 0.f, 0.f, 0.f}, aG = {0.f, 0.f, 0.f, 0.f};
      #pragma unroll
      for (int ks = 0; ks < 8; ++ks) {
        short8v b2h = BRD(sbR, 2, ks), b2l = BRD(sbR, 3, ks);
        aF = MFMA16(ahi[8 + ks], b2h, aF);
        aG = MFMA16(ahi[8 + ks], b2l, aG);
        aG = MFMA16(alo[8 + ks], b2h, aG);
      }
      if (lane < 4) {
        float2 o;
        o.x = aF[0] + aG[0] + bfc0;
        o.y = aF[1] + aG[1] + bfc1;
        *(float2*)(&out[(sG * 4 + lane) * (T_LEN * 2) + (sp - 2) * 2]) = o;
      }
    }

    // ---- check generation bits; re-poll only stale (backoff) ----
    const u32t gb1 = (u32t)(((qp - 1) >> 2) & 1);
    const u32t gb2 = (u32t)(((qp - 2) >> 2) & 1);
    bool ok1 = !ld1 || ((((u32t)v1 >> 30) & 1) == gb1 && (((u32t)(v1 >> 32) >> 30) & 1) == gb1);
    bool ok2 = !ld2 || ((((u32t)v2 >> 30) & 1) == gb2 && (((u32t)(v2 >> 32) >> 30) & 1) == gb2);
    int guard = 0;
    while (!(ok1 && ok2)) {
      __builtin_amdgcn_s_sleep(1);
      if (!ok1) {
        v1 = ALD64(s1);
        ok1 = ((((u32t)v1 >> 30) & 1) == gb1 && (((u32t)(v1 >> 32) >> 30) & 1) == gb1);
      }
      if (!ok2) {
        v2 = ALD64(s2);
        ok2 = ((((u32t)v2 >> 30) & 1) == gb2 && (((u32t)(v2 >> 32) >> 30) & 1) == gb2);
      }
      if (++guard > (1 << 16)) { AST32(abortf, 1u); break; }
      if ((guard & 63) == 0 && ALD32(abortf) != 0) break;
    }

    // ---- unpack (strip gen bit -> exact fp32 -> split bf16 planes) ----
    if (ld1) {
      u32t w0 = (u32t)v1 & 0xBFFFFFFFu, w1 = (u32t)(v1 >> 32) & 0xBFFFFFFFu;
      float f0, f1; __builtin_memcpy(&f0, &w0, 4); __builtin_memcpy(&f1, &w1, 4);
      u32t h0, l0, h1_, l1_;
      split_bf(f0, h0, l0); split_bf(f1, h1_, l1_);
      *(u32t*)(sbW + soff)        = h0 | (h1_ << 16);
      *(u32t*)(sbW + 8192 + soff) = l0 | (l1_ << 16);
    }
    if (ld2) {
      u32t w0 = (u32t)v2 & 0xBFFFFFFFu, w1 = (u32t)(v2 >> 32) & 0xBFFFFFFFu;
      float f0, f1; __builtin_memcpy(&f0, &w0, 4); __builtin_memcpy(&f1, &w1, 4);
      u32t h0, l0, h1_, l1_;
      split_bf(f0, h0, l0); split_bf(f1, h1_, l1_);
      *(u32t*)(sbW + 16384 + soff) = h0 | (h1_ << 16);
      *(u32t*)(sbW + 24576 + soff) = l0 | (l1_ << 16);
    }
    __syncthreads();
  };

  char* LA = lds;
  char* LB = lds + 32768;

  __syncthreads();

  for (int p = 0; p <= T_LEN + 1; ++p) {
    // section A: compute ctxA(p); fetch ctxB data for its phase p
    section(LA, LB, gA, gB, p, p, cstA, ybA);
    // section B: compute ctxB(p); fetch ctxA data for its phase p+1
    section(LB, LA, gB, gA, p, p + 1, cstB, ybB);
  }
}

extern "C" void kernel_launch(void* const* d_in, const int* in_sizes, int n_in,
                              void* d_out, int out_size, void* d_ws, size_t ws_size,
                              hipStream_t stream) {
  const float* y    = (const float*)d_in[0];
  const float* Wih0 = (const float*)d_in[1];
  const float* Whh0 = (const float*)d_in[2];
  const float* bih0 = (const float*)d_in[3];
  const float* bhh0 = (const float*)d_in[4];
  const float* Wih1 = (const float*)d_in[5];
  const float* Whh1 = (const float*)d_in[6];
  const float* bih1 = (const float*)d_in[7];
  const float* bhh1 = (const float*)d_in[8];
  const float* Wfc  = (const float*)d_in[9];
  const float* bfc  = (const float*)d_in[10];
  float* out = (float*)d_out;
  u32t*  ws  = (u32t*)d_ws;

  (void)hipFuncSetAttribute(reinterpret_cast<const void*>(lstm_persist),
                            hipFuncAttributeMaxDynamicSharedMemorySize, 131072);

  hipLaunchKernelGGL(init_ws_kernel, dim3(256), dim3(256), 0, stream, ws);
  hipLaunchKernelGGL(lstm_persist, dim3(256), dim3(NTH), 131072, stream,
                     y, Wih0, Whh0, bih0, bhh0, Wih1, Whh1, bih1, bhh1,
                     Wfc, bfc, out, ws);
}